// Round 11
// baseline (2827.451 us; speedup 1.0000x reference)
//
#include <hip/hip_runtime.h>
#include <stdint.h>

#define LANE ((int)(threadIdx.x & 63))
#define WID  ((int)(threadIdx.x >> 6))

__device__ __forceinline__ float exact_d2(float ax, float ay, float az,
                                          float bx, float by, float bz) {
  float dx = ax - bx, dy = ay - by, dz = az - bz;
  return __fadd_rn(__fadd_rn(__fmul_rn(dx, dx), __fmul_rn(dy, dy)), __fmul_rn(dz, dz));
}

__device__ __forceinline__ void lds_fence() {
  asm volatile("s_waitcnt lgkmcnt(0)" ::: "memory");
}

// Barrier that does NOT drain vmcnt: LDS-visibility fence + raw s_barrier.
__device__ __forceinline__ void lds_barrier() {
  asm volatile("s_waitcnt lgkmcnt(0)" ::: "memory");
  __builtin_amdgcn_s_barrier();
  asm volatile("" ::: "memory");
}

// Wave-wide max via DPP. ROW_SHR 1/2/4/8 accumulates row maxima into lanes
// 15/31/47/63; row_bcast15 (rows 1,3) then row_bcast31 (rows 2,3) fold rows;
// lane 63 holds the full wave max. (R7-verified.)
__device__ __forceinline__ float wave_max_dpp(float v) {
  const int NI = 0xff800000;  // -inf bits: identity
  int x = __float_as_int(v);
  x = __float_as_int(fmaxf(__int_as_float(x),
      __int_as_float(__builtin_amdgcn_update_dpp(NI, x, 0x111, 0xf, 0xf, false))));
  x = __float_as_int(fmaxf(__int_as_float(x),
      __int_as_float(__builtin_amdgcn_update_dpp(NI, x, 0x112, 0xf, 0xf, false))));
  x = __float_as_int(fmaxf(__int_as_float(x),
      __int_as_float(__builtin_amdgcn_update_dpp(NI, x, 0x114, 0xf, 0xf, false))));
  x = __float_as_int(fmaxf(__int_as_float(x),
      __int_as_float(__builtin_amdgcn_update_dpp(NI, x, 0x118, 0xf, 0xf, false))));
  x = __float_as_int(fmaxf(__int_as_float(x),
      __int_as_float(__builtin_amdgcn_update_dpp(NI, x, 0x142, 0xa, 0xf, false))));
  x = __float_as_int(fmaxf(__int_as_float(x),
      __int_as_float(__builtin_amdgcn_update_dpp(NI, x, 0x143, 0xc, 0xf, false))));
  return __int_as_float(__builtin_amdgcn_readlane(x, 63));
}

// ---------------- FPS loop: single LDS round per iteration ----------------
// Per iter: dd update with inline (lv, li, bx,by,bz) tracking -> DPP wave max ->
// ballot picks lowest winning lane -> winner publishes {idxkey, distbits, x, y}
// (ds_write_b128) + z (b32) to parity slot -> lds_barrier -> all threads read the
// 4 slots in one burst (one lgkmcnt wait) -> cndmask merge web yields winner key
// AND coords together. No second dependent LDS read. tid0 logs to global/table.
template <int PT, int NPTS, int NSAMP, bool LOGP, bool TAB>
__device__ __forceinline__ void fps_loop(float* px, float* py, float* pz, float* dd,
                                         int i0, float fx, float fy, float fz, int b,
                                         int* __restrict__ out_idx,
                                         float* __restrict__ out_pos, float* tabx,
                                         float* taby, float* tabz, uint4* kxy,
                                         float* kz) {
  const int lane = LANE, wid = WID, tid = (int)threadIdx.x;
  for (int s = 1; s < NSAMP; ++s) {
    float lv = -__builtin_inff();
    int li = 0;
    float bx = px[0], by = py[0], bz = pz[0];
#pragma unroll
    for (int k = 0; k < PT; ++k) {
      float d = exact_d2(px[k], py[k], pz[k], fx, fy, fz);
      float nd = fminf(dd[k], d);
      dd[k] = nd;
      bool gt = nd > lv;  // strict >: first k within thread wins ties
      lv = gt ? nd : lv;
      li = gt ? k : li;
      bx = gt ? px[k] : bx;
      by = gt ? py[k] : by;
      bz = gt ? pz[k] : bz;
    }
    const float wv = wave_max_dpp(lv);
    const uint64_t mball = __ballot(lv == wv);
    const int wl = (int)__ffsll((unsigned long long)mball) - 1;  // lowest lane
    const int par = s & 1;
    if (lane == wl) {  // one b128 + one b32, issued together
      kxy[par * 4 + wid] =
          make_uint4((unsigned)(NPTS - 1 - (i0 + li)), __float_as_uint(wv),
                     __float_as_uint(bx), __float_as_uint(by));
      kz[par * 4 + wid] = bz;
    }
    lds_barrier();  // all 4 slots fresh (every wave has a winner)
    const uint4 a0 = kxy[par * 4 + 0], a1 = kxy[par * 4 + 1];
    const uint4 a2 = kxy[par * 4 + 2], a3 = kxy[par * 4 + 3];
    const float z0 = kz[par * 4 + 0], z1 = kz[par * 4 + 1];
    const float z2 = kz[par * 4 + 2], z3 = kz[par * 4 + 3];
    const uint64_t k0 = ((uint64_t)a0.y << 32) | a0.x;
    const uint64_t k1 = ((uint64_t)a1.y << 32) | a1.x;
    const uint64_t k2 = ((uint64_t)a2.y << 32) | a2.x;
    const uint64_t k3 = ((uint64_t)a3.y << 32) | a3.x;
    const bool t01 = k1 > k0;
    const uint64_t k01 = t01 ? k1 : k0;
    const unsigned x01 = t01 ? a1.z : a0.z, y01 = t01 ? a1.w : a0.w;
    const float z01 = t01 ? z1 : z0;
    const bool t23 = k3 > k2;
    const uint64_t k23 = t23 ? k3 : k2;
    const unsigned x23 = t23 ? a3.z : a2.z, y23 = t23 ? a3.w : a2.w;
    const float z23 = t23 ? z3 : z2;
    const bool tf = k23 > k01;
    const uint64_t kf = tf ? k23 : k01;
    fx = __uint_as_float(tf ? x23 : x01);
    fy = __uint_as_float(tf ? y23 : y01);
    fz = tf ? z23 : z01;
    if (tid == 0) {
      const int widx = (NPTS - 1) - (int)(unsigned)(kf & 0xFFFFFFFFu);
      out_idx[(size_t)b * NSAMP + s] = widx;
      if (LOGP) {
        out_pos[((size_t)b * NSAMP + s) * 3 + 0] = fx;
        out_pos[((size_t)b * NSAMP + s) * 3 + 1] = fy;
        out_pos[((size_t)b * NSAMP + s) * 3 + 2] = fz;
      }
      if (TAB) {
        tabx[s] = fx; taby[s] = fy; tabz[s] = fz;
      }
    }
  }
}

// ------- fused FPS block: pass 1 (4096->2048) then pass 2 (2048->512) -------
// Pass 1 logs samples into an LDS table; pass 2 runs on the table in the same
// block -- stage2 then carries no FPS tail (pure conv2).
__device__ void fps_fused_body(const float* __restrict__ coords, int b,
                               int* __restrict__ I1, float* __restrict__ P1,
                               int* __restrict__ I2, char* smem) {
  float* tabx = (float*)smem;          // [2048]
  float* taby = tabx + 2048;           // [2048]
  float* tabz = taby + 2048;           // [2048]
  uint4* kxy = (uint4*)(tabz + 2048);  // [8]
  float* kz = (float*)(kxy + 8);       // [8]
  const int tid = (int)threadIdx.x;
  const float* pos = coords + (size_t)b * 4096 * 3;

  __builtin_amdgcn_s_setprio(3);  // FPS is the serial critical path

  {  // ---- pass 1: 4096 -> 2048, PT=16 ----
    float px[16], py[16], pz[16], dd[16];
    const int i0 = tid * 16;
#pragma unroll
    for (int k = 0; k < 16; ++k) {
      px[k] = pos[(i0 + k) * 3 + 0];
      py[k] = pos[(i0 + k) * 3 + 1];
      pz[k] = pos[(i0 + k) * 3 + 2];
      dd[k] = __builtin_inff();
    }
    const float fx = pos[0], fy = pos[1], fz = pos[2];
    if (tid == 0) {
      I1[(size_t)b * 2048] = 0;
      P1[(size_t)b * 2048 * 3 + 0] = fx;
      P1[(size_t)b * 2048 * 3 + 1] = fy;
      P1[(size_t)b * 2048 * 3 + 2] = fz;
      tabx[0] = fx; taby[0] = fy; tabz[0] = fz;
    }
    __syncthreads();
    fps_loop<16, 4096, 2048, true, true>(px, py, pz, dd, i0, fx, fy, fz, b, I1, P1,
                                         tabx, taby, tabz, kxy, kz);
  }
  __syncthreads();  // sample table complete & visible
  {  // ---- pass 2: 2048 -> 512, PT=8, points from LDS table ----
    float px[8], py[8], pz[8], dd[8];
    const int i0 = tid * 8;
#pragma unroll
    for (int k = 0; k < 8; ++k) {
      px[k] = tabx[i0 + k];
      py[k] = taby[i0 + k];
      pz[k] = tabz[i0 + k];
      dd[k] = __builtin_inff();
    }
    const float fx = tabx[0], fy = taby[0], fz = tabz[0];
    if (tid == 0) I2[(size_t)b * 512] = 0;
    __syncthreads();
    fps_loop<8, 2048, 512, false, false>(px, py, pz, dd, i0, fx, fy, fz, b, I2,
                                         nullptr, nullptr, nullptr, nullptr, kxy, kz);
  }
}

// ---- exact neighbor selection: in-radius candidates, 64 nearest (d, then j) ----
template <int NPTS, int CAP>
__device__ __forceinline__ int select_neighbors(const float* __restrict__ bpos,
                                                float qx, float qy, float qz, float r2,
                                                char* wmem, unsigned* jl) {
  constexpr int SLOTS = CAP / 64;
  const int lane = LANE;
  uint64_t* list = (uint64_t*)wmem;
  const uint64_t ltmask = (1ull << lane) - 1ull;

  unsigned cnt = 0;
  for (int base = 0; base < NPTS; base += 64) {
    int j = base + lane;
    float d = exact_d2(bpos[j * 3], bpos[j * 3 + 1], bpos[j * 3 + 2], qx, qy, qz);
    bool pred = d < r2;
    uint64_t mask = __ballot(pred);
    if (pred) {
      unsigned p = cnt + (unsigned)__popcll(mask & ltmask);
      if (p < CAP) list[p] = ((uint64_t)__float_as_uint(d) << 32) | (unsigned)j;
    }
    cnt += (unsigned)__popcll(mask);
  }
  if (cnt > CAP) cnt = CAP;
  lds_fence();

  int m;
  if (cnt <= 64) {
    m = (int)cnt;
    jl[lane] = (lane < m) ? (unsigned)list[lane] : 0u;
  } else {
    m = 64;
    uint64_t e[SLOTS];
#pragma unroll
    for (int si = 0; si < SLOTS; ++si) {
      int p = lane + 64 * si;
      e[si] = (p < (int)cnt) ? list[p] : ~0ull;
    }
    // binary search for d* = 64th smallest distance bit-pattern
    unsigned lo = 0, hi = 0x3F800000u;
    while (lo < hi) {
      unsigned mid = (lo + hi) >> 1;
      unsigned c = 0;
#pragma unroll
      for (int si = 0; si < SLOTS; ++si)
        c += (unsigned)__popcll(__ballot((unsigned)(e[si] >> 32) <= mid));
      if (c >= 64u) hi = mid; else lo = mid + 1;
    }
    const unsigned dstar = lo;
    unsigned nlt = 0, nt = 0;
#pragma unroll
    for (int si = 0; si < SLOTS; ++si) {
      unsigned hb = (unsigned)(e[si] >> 32);
      nlt += (unsigned)__popcll(__ballot(hb < dstar));
      nt += (unsigned)__popcll(__ballot(hb == dstar));
    }
    const unsigned need = 64u - nlt;
    unsigned jsel = 0xFFFFFFFFu;
    if (nt != need) {  // distance tie at the cut -> keep `need` smallest j
      unsigned jlo = 0, jhi = (unsigned)NPTS - 1;
      while (jlo < jhi) {
        unsigned jmid = (jlo + jhi) >> 1;
        unsigned c = 0;
#pragma unroll
        for (int si = 0; si < SLOTS; ++si)
          c += (unsigned)__popcll(__ballot(
              ((unsigned)(e[si] >> 32) == dstar) && ((unsigned)e[si] <= jmid)));
        if (c >= need) jhi = jmid; else jlo = jmid + 1;
      }
      jsel = jlo;
    }
    unsigned c2 = 0;
#pragma unroll
    for (int si = 0; si < SLOTS; ++si) {
      unsigned hb = (unsigned)(e[si] >> 32), jj = (unsigned)e[si];
      bool p = (hb < dstar) || ((hb == dstar) && (jj <= jsel));
      uint64_t mask = __ballot(p);
      if (p) jl[c2 + (unsigned)__popcll(mask & ltmask)] = jj;
      c2 += (unsigned)__popcll(mask);
    }
  }
  lds_fence();
  return m;
}

// ---------------- conv1: H=64, lane = neighbor, y1[64] in regs ----------------
__device__ void conv1_body(const float* __restrict__ pos, const float* __restrict__ feats,
                           const float* __restrict__ w1, const float* __restrict__ b1,
                           const float* __restrict__ w2t, const float* __restrict__ b2,
                           float* __restrict__ out, int qid, char* wmem) {
  const int lane = LANE;
  const int b = qid >> 12, qi = qid & 4095;
  const float* bpos = pos + (size_t)b * 4096 * 3;
  const float qx = bpos[qi * 3 + 0], qy = bpos[qi * 3 + 1], qz = bpos[qi * 3 + 2];
  unsigned* jl = (unsigned*)(wmem + 8320);
  const int m = select_neighbors<4096, 512>(bpos, qx, qy, qz, 0.04f, wmem, jl);

  const bool valid = lane < m;
  const int j = valid ? (int)jl[lane] : 0;
  const float rx = bpos[j * 3 + 0] - qx;
  const float ry = bpos[j * 3 + 1] - qy;
  const float rz = bpos[j * 3 + 2] - qz;
  const float* xr = feats + ((size_t)b * 4096 + j) * 6;
  const float x0 = xr[0], x1 = xr[1], x2 = xr[2], x3 = xr[3], x4 = xr[4], x5 = xr[5];
  const float* w1r = w1 + 6 * 64;

  float y1[64];
#pragma unroll
  for (int f = 0; f < 64; ++f) {
    float a = b1[f];
    a = fmaf(x0, w1[0 * 64 + f], a);
    a = fmaf(x1, w1[1 * 64 + f], a);
    a = fmaf(x2, w1[2 * 64 + f], a);
    a = fmaf(x3, w1[3 * 64 + f], a);
    a = fmaf(x4, w1[4 * 64 + f], a);
    a = fmaf(x5, w1[5 * 64 + f], a);
    a = fmaf(rx, w1r[0 * 64 + f], a);
    a = fmaf(ry, w1r[1 * 64 + f], a);
    a = fmaf(rz, w1r[2 * 64 + f], a);
    y1[f] = fmaxf(a, 0.0f);
  }

  float* stg = (float*)wmem;  // [32][65], reuses candidate area
  float* orow = out + (size_t)qid * 64;
  const float NEG = -__builtin_inff();
#pragma unroll 1
  for (int cst = 0; cst < 64; cst += 32) {
    lds_fence();
#pragma unroll 1
    for (int g = 0; g < 32; ++g) {
      const float* wrow = w2t + (size_t)(cst + g) * 64;  // uniform -> s_load
      float a0 = 0.f, a1 = 0.f, a2 = 0.f, a3 = 0.f;
#pragma unroll
      for (int f = 0; f < 64; f += 4) {
        a0 = fmaf(y1[f], wrow[f], a0);
        a1 = fmaf(y1[f + 1], wrow[f + 1], a1);
        a2 = fmaf(y1[f + 2], wrow[f + 2], a2);
        a3 = fmaf(y1[f + 3], wrow[f + 3], a3);
      }
      float acc = b2[cst + g] + ((a0 + a1) + (a2 + a3));
      stg[g * 65 + lane] = valid ? acc : NEG;
    }
    lds_fence();
    const int r = lane & 31, jb = lane & 32;
    float mx = NEG;
#pragma unroll
    for (int t = 0; t < 32; ++t) mx = fmaxf(mx, stg[r * 65 + jb + t]);
    mx = fmaxf(mx, __shfl_xor(mx, 32));
    if (lane < 32) orow[cst + lane] = mx;
  }
}

// ------- conv2: H=128, TWO waves per query (wave-uniform feature half) -------
__device__ void conv2_body(const float* __restrict__ pos, const float* __restrict__ u,
                           const float* __restrict__ w1r, const float* __restrict__ w2t,
                           const float* __restrict__ b2, float* __restrict__ out,
                           int qid, int half, char* wmem, char* pairmem) {
  const int lane = LANE;
  const int b = qid >> 11, qi = qid & 2047;
  const float* bpos = pos + (size_t)b * 2048 * 3;
  const float qx = bpos[qi * 3 + 0], qy = bpos[qi * 3 + 1], qz = bpos[qi * 3 + 2];
  unsigned* jl = (unsigned*)(wmem + 8320);
  const int m = select_neighbors<2048, 1024>(bpos, qx, qy, qz, 0.16f, wmem, jl);
  const int fh = half * 64;

  const bool valid = lane < m;
  const int j = valid ? (int)jl[lane] : 0;
  const float rx = bpos[j * 3 + 0] - qx;
  const float ry = bpos[j * 3 + 1] - qy;
  const float rz = bpos[j * 3 + 2] - qz;
  const float* urow = u + ((size_t)b * 2048 + j) * 128 + fh;

  float y1[64];
#pragma unroll
  for (int t = 0; t < 64; t += 4) {
    float4 v = *reinterpret_cast<const float4*>(urow + t);
    y1[t] = v.x; y1[t + 1] = v.y; y1[t + 2] = v.z; y1[t + 3] = v.w;
  }
#pragma unroll
  for (int t = 0; t < 64; ++t) {
    float a = fmaf(rx, w1r[0 * 128 + fh + t], y1[t]);
    a = fmaf(ry, w1r[1 * 128 + fh + t], a);
    a = fmaf(rz, w1r[2 * 128 + fh + t], a);
    y1[t] = fmaxf(a, 0.0f);
  }

  float* stgA = (float*)pairmem;           // half-0 wave's [32][65]
  float* stgB = (float*)(pairmem + 8704);  // half-1 wave's [32][65]
  float* stg_own = half ? stgB : stgA;     // == wmem
  float* orow = out + (size_t)qid * 128;
  const float NEG = -__builtin_inff();
#pragma unroll 1
  for (int cst = 0; cst < 128; cst += 32) {
#pragma unroll 1
    for (int g = 0; g < 32; ++g) {
      const float* wrow = w2t + (size_t)(cst + g) * 128 + fh;  // uniform -> s_load
      float a0 = 0.f, a1 = 0.f, a2 = 0.f, a3 = 0.f;
#pragma unroll
      for (int t = 0; t < 64; t += 4) {
        a0 = fmaf(y1[t], wrow[t], a0);
        a1 = fmaf(y1[t + 1], wrow[t + 1], a1);
        a2 = fmaf(y1[t + 2], wrow[t + 2], a2);
        a3 = fmaf(y1[t + 3], wrow[t + 3], a3);
      }
      float pc = (a0 + a1) + (a2 + a3);
      stg_own[g * 65 + lane] = valid ? pc : (half ? 0.0f : NEG);
    }
    __syncthreads();
    if (half == 0) {
      const int r = lane & 31, jb = (lane >> 5) * 32;
      float mx = NEG;
#pragma unroll
      for (int t = 0; t < 32; ++t)
        mx = fmaxf(mx, stgA[r * 65 + jb + t] + stgB[r * 65 + jb + t]);
      mx = fmaxf(mx, __shfl_xor(mx, 32));
      if (lane < 32) orow[cst + lane] = mx + b2[cst + lane];
    }
    __syncthreads();
  }
}

// ------- stage 1: blocks 0..7 = fused fps1+fps2, rest = conv1 -------
__global__ __launch_bounds__(256, 2) void stage1_kernel(
    const float* __restrict__ coords, const float* __restrict__ feats,
    const float* __restrict__ w1, const float* __restrict__ b1,
    const float* __restrict__ w2t, const float* __restrict__ b2,
    float* __restrict__ out, int* __restrict__ fps_idx, float* __restrict__ fps_pos,
    int* __restrict__ fps_idx2) {
  __shared__ __align__(16) char smem[36352];  // fps: 24.8KB; conv: 4 x 9088
  if (blockIdx.x < 8) {
    fps_fused_body(coords, (int)blockIdx.x, fps_idx, fps_pos, fps_idx2, smem);
  } else {
    int qid = __builtin_amdgcn_readfirstlane(((int)blockIdx.x - 8) * 4 + WID);
    conv1_body(coords, feats, w1, b1, w2t, b2, out, qid, smem + WID * 9088);
  }
}

// ------- stage 2: pure conv2 (fps2 moved into stage 1) -------
__global__ __launch_bounds__(256, 2) void stage2_kernel(
    const float* __restrict__ p1, const float* __restrict__ u2,
    const float* __restrict__ w1r, const float* __restrict__ w2t,
    const float* __restrict__ b2, float* __restrict__ out) {
  __shared__ __align__(16) char smem[34816];  // 2 pairs x (2 x 8704)
  const int wid = WID;
  const int half = __builtin_amdgcn_readfirstlane(wid & 1);
  const int qid = __builtin_amdgcn_readfirstlane((int)blockIdx.x * 2 + (wid >> 1));
  conv2_body(p1, u2, w1r, w2t, b2, out, qid, half, smem + wid * 8704,
             smem + (wid & ~1) * 8704);
}

// ------- u2 = b1b + h1[i1] @ W1b_feat (layer-1 factoring for stage 2) -------
__global__ __launch_bounds__(128) void u2_kernel(const float* __restrict__ h1,
                                                 const int* __restrict__ i1,
                                                 const float* __restrict__ w1,
                                                 const float* __restrict__ b1,
                                                 float* __restrict__ u2) {
  int row = blockIdx.x;  // 16384
  int f = (int)threadIdx.x;
  int b = row >> 11;
  int src = i1[row];
  const float* x = h1 + ((size_t)b * 4096 + src) * 64;
  float acc = b1[f];
#pragma unroll
  for (int k = 0; k < 64; ++k) acc = fmaf(x[k], w1[k * 128 + f], acc);
  u2[(size_t)row * 128 + f] = acc;
}

__global__ __launch_bounds__(256) void transpose_kernel(const float* __restrict__ w2a,
                                                        const float* __restrict__ w2b,
                                                        float* __restrict__ w2ta,
                                                        float* __restrict__ w2tb) {
  int gtid = blockIdx.x * 256 + (int)threadIdx.x;
  int stride = gridDim.x * 256;
  for (int t = gtid; t < 64 * 64; t += stride) w2ta[(t & 63) * 64 + (t >> 6)] = w2a[t];
  for (int t = gtid; t < 128 * 128; t += stride) w2tb[(t & 127) * 128 + (t >> 7)] = w2b[t];
}

// ---------------- global max pool over i2 + final linear ----------------
__global__ __launch_bounds__(512) void pool_linear_kernel(
    const float* __restrict__ h2, const int* __restrict__ i2,
    const float* __restrict__ wl, const float* __restrict__ bl,
    float* __restrict__ out) {
  int b = blockIdx.x;
  int c = (int)threadIdx.x >> 7;
  int f = (int)threadIdx.x & 127;
  __shared__ float part[4][128];
  __shared__ float feat[128];
  float mx = -__builtin_inff();
  const int* idx = i2 + b * 512;
  for (int s = c * 128; s < c * 128 + 128; ++s) {
    int j = idx[s];
    mx = fmaxf(mx, h2[((size_t)b * 2048 + j) * 128 + f]);
  }
  part[c][f] = mx;
  __syncthreads();
  if (c == 0) {
    feat[f] = fmaxf(fmaxf(part[0][f], part[1][f]), fmaxf(part[2][f], part[3][f]));
  }
  __syncthreads();
  if (c == 0) {
    float acc = bl[f];
#pragma unroll
    for (int k = 0; k < 128; ++k) acc = fmaf(feat[k], wl[k * 128 + f], acc);
    out[b * 128 + f] = acc;
  }
}

extern "C" void kernel_launch(void* const* d_in, const int* in_sizes, int n_in,
                              void* d_out, int out_size, void* d_ws, size_t ws_size,
                              hipStream_t stream) {
  const float* feats = (const float*)d_in[0];   // [8,4096,6]
  const float* coords = (const float*)d_in[1];  // [8,4096,3]
  const float* W1a = (const float*)d_in[2];     // [9,64]
  const float* b1a = (const float*)d_in[3];
  const float* W2a = (const float*)d_in[4];     // [64,64]
  const float* b2a = (const float*)d_in[5];
  const float* W1b = (const float*)d_in[6];     // [67,128]
  const float* b1b = (const float*)d_in[7];
  const float* W2b = (const float*)d_in[8];     // [128,128]
  const float* b2b = (const float*)d_in[9];
  const float* Wl = (const float*)d_in[10];     // [128,128]
  const float* bl = (const float*)d_in[11];

  float* ws = (float*)d_ws;
  float* W2TA = ws;                  // 4096
  float* W2TB = W2TA + 4096;         // 16384
  float* H1 = W2TB + 16384;          // 8*4096*64  = 2097152
  float* U2 = H1 + 2097152;          // 8*2048*128 = 2097152
  float* H2 = U2 + 2097152;          // 8*2048*128 = 2097152
  float* P1 = H2 + 2097152;          // 8*2048*3   = 49152
  int* I1 = (int*)(P1 + 49152);      // 8*2048
  int* I2 = I1 + 16384;              // 8*512

  transpose_kernel<<<80, 256, 0, stream>>>(W2a, W2b, W2TA, W2TB);
  // stage 1: fps1+fps2 fused (blocks 0-7) || conv1 (8192 blocks x 4 queries)
  stage1_kernel<<<8 + 8192, 256, 0, stream>>>(coords, feats, W1a, b1a, W2TA, b2a, H1,
                                              I1, P1, I2);
  u2_kernel<<<16384, 128, 0, stream>>>(H1, I1, W1b, b1b, U2);
  // stage 2: conv2 only (8192 blocks x 2 queries x 2 waves)
  stage2_kernel<<<8192, 256, 0, stream>>>(P1, U2, W1b + 64 * 128, W2TB, b2b, H2);
  pool_linear_kernel<<<8, 512, 0, stream>>>(H2, I2, Wl, bl, (float*)d_out);
}